// Round 6
// baseline (92.668 us; speedup 1.0000x reference)
//
#include <hip/hip_runtime.h>

#define N 4096
#define BLOCK 256
#define JC 64                 // j-chunks (grid.y)
#define JCHUNK (N / JC)       // 64 j's per chunk
#define NBX (N / BLOCK)       // 16 i-blocks (grid.x)
#define CNT_OFF ((size_t)JC * 3 * N)   // float offset of counters in ws

// ---- per-pair body: wave-uniform j reads -> scalar loads, rcp for 1/r2 ----
template <bool DIAG>
__device__ __forceinline__ void lj_accum(const float* __restrict__ qj, int j0, int i,
                                         float qx, float qy, float qz,
                                         float& fx, float& fy, float& fz) {
    #pragma unroll 8
    for (int jj = 0; jj < JCHUNK; ++jj) {
        const float dx = qx - qj[jj * 3 + 0];   // wave-uniform -> s_load
        const float dy = qy - qj[jj * 3 + 1];
        const float dz = qz - qj[jj * 3 + 2];
        const float r2 = fmaf(dx, dx, fmaf(dy, dy, dz * dz));
        const float inv_r2 = __builtin_amdgcn_rcpf(r2);    // v_rcp_f32
        const float inv_r4 = inv_r2 * inv_r2;
        const float inv_r6 = inv_r4 * inv_r2;
        const float inv_r8 = inv_r4 * inv_r4;
        float s = inv_r8 * fmaf(-48.0f, inv_r6, 24.0f);    // 24 r^-8 - 48 r^-14
        if (DIAG) s = (j0 + jj == i) ? 0.0f : s;           // predicated
        fx = fmaf(s, dx, fx);
        fy = fmaf(s, dy, fy);
        fz = fmaf(s, dz, fz);
    }
}

// ---- single-dispatch kernel: partials + dq, then last-block-per-column
//      reduces that column's partials -> dp. cnt[] zeroed by memset node. ----
__global__ __launch_bounds__(BLOCK)
void lj_onepass_kernel(const float* __restrict__ q, const float* __restrict__ p,
                       const float* __restrict__ m, float* __restrict__ out,
                       float* __restrict__ ws, int* __restrict__ cnt) {
    const int bx  = blockIdx.x;          // i-block (16)
    const int by  = blockIdx.y;          // j-chunk (64)
    const int tid = threadIdx.x;
    const int i   = bx * BLOCK + tid;

    {   // phase 1: atomic-free partials -> ws[(by*3+c)*N + i]
        const int j0 = by * JCHUNK;
        const float* __restrict__ qj = q + j0 * 3;
        const float qx = q[i*3+0], qy = q[i*3+1], qz = q[i*3+2];
        float fx = 0.f, fy = 0.f, fz = 0.f;
        if ((by >> 2) == bx)
            lj_accum<true >(qj, j0, i, qx, qy, qz, fx, fy, fz);
        else
            lj_accum<false>(qj, j0, i, qx, qy, qz, fx, fy, fz);
        float* w = ws + (size_t)by * 3 * N;
        w[0*N + i] = fx;                 // coalesced SoA stores
        w[1*N + i] = fy;
        w[2*N + i] = fz;
    }

    if (by == 0) {                       // fold dq = p/m into 16 blocks
        const int base = bx * (BLOCK * 3);
        #pragma unroll
        for (int k = 0; k < 3; ++k) {
            const int t = base + k * BLOCK + tid;
            out[t] = p[t] / m[t / 3];
        }
    }

    // ---- last-block-done reduction for this i-column ----
    __shared__ int is_last;
    __threadfence();                     // release: partials visible device-wide
    if (tid == 0)
        is_last = (atomicAdd(&cnt[bx], 1) == JC - 1);
    __syncthreads();
    if (is_last) {
        __threadfence();                 // acquire: see all columns' stores
        #pragma unroll
        for (int c = 0; c < 3; ++c) {
            float acc = 0.f;
            #pragma unroll 8
            for (int k = 0; k < JC; ++k)
                acc += ws[(size_t)(k * 3 + c) * N + i];   // coalesced per k
            out[N*3 + i*3 + c] = acc;
        }
    }
}

// ---- fallback: proven R4 two-kernel path ----------------------------------
__global__ __launch_bounds__(BLOCK)
void lj_partial_kernel(const float* __restrict__ q, float* __restrict__ ws) {
    const int bx = blockIdx.x, by = blockIdx.y;
    const int i  = bx * BLOCK + threadIdx.x;
    const int j0 = by * JCHUNK;
    const float* __restrict__ qj = q + j0 * 3;
    const float qx = q[i*3+0], qy = q[i*3+1], qz = q[i*3+2];
    float fx = 0.f, fy = 0.f, fz = 0.f;
    if ((by >> 2) == bx)
        lj_accum<true >(qj, j0, i, qx, qy, qz, fx, fy, fz);
    else
        lj_accum<false>(qj, j0, i, qx, qy, qz, fx, fy, fz);
    float* w = ws + (size_t)by * 3 * N;
    w[0*N + i] = fx;  w[1*N + i] = fy;  w[2*N + i] = fz;
}

__global__ __launch_bounds__(BLOCK)
void lj_reduce_kernel(const float* __restrict__ ws, const float* __restrict__ p,
                      const float* __restrict__ m, float* __restrict__ out) {
    const int u = blockIdx.x * BLOCK + threadIdx.x;
    out[u] = p[u] / m[u / 3];
    const int c = u >> 12;
    const int i = u & (N - 1);
    float acc = 0.f;
    #pragma unroll 8
    for (int k = 0; k < JC; ++k)
        acc += ws[(size_t)(k * 3 + c) * N + i];
    out[N*3 + i*3 + c] = acc;
}

extern "C" void kernel_launch(void* const* d_in, const int* in_sizes, int n_in,
                              void* d_out, int out_size, void* d_ws, size_t ws_size,
                              hipStream_t stream) {
    const float* q = (const float*)d_in[0];
    const float* p = (const float*)d_in[1];
    const float* m = (const float*)d_in[2];
    float* out = (float*)d_out;
    float* ws  = (float*)d_ws;

    if (ws_size >= CNT_OFF * sizeof(float) + NBX * sizeof(int)) {
        int* cnt = (int*)(ws + CNT_OFF);
        hipMemsetAsync(cnt, 0, NBX * sizeof(int), stream);   // 64 B memset node
        dim3 grid(NBX, JC);
        lj_onepass_kernel<<<grid, BLOCK, 0, stream>>>(q, p, m, out, ws, cnt);
    } else {
        dim3 grid(NBX, JC);
        lj_partial_kernel<<<grid, BLOCK, 0, stream>>>(q, ws);
        lj_reduce_kernel<<<(N * 3) / BLOCK, BLOCK, 0, stream>>>(ws, p, m, out);
    }
}

// Round 8
// 14.916 us; speedup vs baseline: 6.2128x; 6.2128x over previous
//
#include <hip/hip_runtime.h>

#define N 4096
#define BLOCK 512             // 8 waves/block, one particle i per wave
#define NB (N / 8)            // 512 blocks, 2 per CU
#define NSTEP (N / 64)        // 64 j-steps per wave (one j per lane per step)

// Single-dispatch kernel:
//  - stage all of q (48 KB) into LDS
//  - wave w computes full force on particle i = blockIdx.x*8 + w:
//    64 steps, lane l handles j = step*64 + l (stride-3 banks -> 2 lanes/bank, free)
//  - 6-step shfl_xor butterfly reduces (fx,fy,fz); lane 0 stores dp[i]
//  - dq = p/m folded in (24 elements per block)
__global__ __launch_bounds__(BLOCK, 4)
void lj_single_kernel(const float* __restrict__ q, const float* __restrict__ p,
                      const float* __restrict__ m, float* __restrict__ out) {
    __shared__ float qs[N * 3];          // 48 KB
    const int tid  = threadIdx.x;
    const int lane = tid & 63;
    const int wave = tid >> 6;           // 0..7
    const int i    = blockIdx.x * 8 + wave;

    // own particle position: wave-uniform -> scalar loads
    const float qx = q[i * 3 + 0];
    const float qy = q[i * 3 + 1];
    const float qz = q[i * 3 + 2];

    // stage q into LDS, float4-coalesced: 3072 float4 / 512 threads = 6 each
    {
        const float4* __restrict__ q4 = (const float4*)q;
        float4* __restrict__ qs4 = (float4*)qs;
        #pragma unroll
        for (int k = 0; k < (N * 3) / 4 / BLOCK; ++k)
            qs4[k * BLOCK + tid] = q4[k * BLOCK + tid];
    }
    __syncthreads();

    float fx = 0.f, fy = 0.f, fz = 0.f;
    const int sdiag = i >> 6;            // the step whose j-window contains i

    #pragma unroll 4
    for (int st = 0; st < NSTEP; ++st) {
        const int j = st * 64 + lane;
        const float dx = qx - qs[j * 3 + 0];
        const float dy = qy - qs[j * 3 + 1];
        const float dz = qz - qs[j * 3 + 2];
        const float r2 = fmaf(dx, dx, fmaf(dy, dy, dz * dz));
        const float u1 = __builtin_amdgcn_rcpf(r2);   // r^-2  (v_rcp_f32)
        const float u2 = u1 * u1;                     // r^-4
        const float u3 = u2 * u1;                     // r^-6
        const float u4 = u2 * u2;                     // r^-8
        float s = u4 * fmaf(-48.0f, u3, 24.0f);       // 24 r^-8 - 48 r^-14
        if (st == sdiag)                 // wave-uniform branch, 1 of 64 steps
            s = (j == i) ? 0.0f : s;
        fx = fmaf(s, dx, fx);
        fy = fmaf(s, dy, fy);
        fz = fmaf(s, dz, fz);
    }

    // in-register wave reduction (fixed order -> deterministic)
    #pragma unroll
    for (int off = 32; off > 0; off >>= 1) {
        fx += __shfl_xor(fx, off, 64);
        fy += __shfl_xor(fy, off, 64);
        fz += __shfl_xor(fz, off, 64);
    }
    if (lane == 0) {
        out[N * 3 + i * 3 + 0] = fx;
        out[N * 3 + i * 3 + 1] = fy;
        out[N * 3 + i * 3 + 2] = fz;
    }

    // dq = p / m : 12288 elems over 512 blocks = 24 per block
    if (tid < (N * 3) / NB) {
        const int u = blockIdx.x * ((N * 3) / NB) + tid;
        out[u] = p[u] / m[u / 3];
    }
}

extern "C" void kernel_launch(void* const* d_in, const int* in_sizes, int n_in,
                              void* d_out, int out_size, void* d_ws, size_t ws_size,
                              hipStream_t stream) {
    const float* q = (const float*)d_in[0];
    const float* p = (const float*)d_in[1];
    const float* m = (const float*)d_in[2];
    float* out = (float*)d_out;

    lj_single_kernel<<<NB, BLOCK, 0, stream>>>(q, p, m, out);
}